// Round 1
// baseline (601.552 us; speedup 1.0000x reference)
//
#include <hip/hip_runtime.h>
#include <math.h>

#define BB 16
#define SS 8192
#define HH 768
#define NH 12
#define HD 64
#define SCALE 0.125f

// ws layout (float offsets)
#define WS_QKP  0                      // NH*HH = 9216
#define WS_C    9216                   // 16
#define WS_GATE 9232                   // 768
#define WS_SC   10240                  // BB*NH*SS = 1572864
#define WS_PART (10240 + 1572864)      // BB*32*NH*HH = 4718592
#define WS_POOL (WS_PART + 4718592)    // BB*NH*HH = 147456

// ---------------- K0: precompute qkp (scale*Wk^T q), score bias c, gate ----------------
__global__ __launch_bounds__(256) void k_pre(const float* __restrict__ query,
                                             const float* __restrict__ w_kv,
                                             const float* __restrict__ b_kv,
                                             const float* __restrict__ w_gate,
                                             const float* __restrict__ b_gate,
                                             float* __restrict__ ws) {
    int blk = blockIdx.x, t = threadIdx.x;
    if (blk < 36) {
        // qkp[h][j] = scale * sum_d query[h*64+d] * w_kv[h*64+d][j]
        int h = blk / 3;
        int j = (blk % 3) * 256 + t;
        float acc = 0.f;
        #pragma unroll 8
        for (int d = 0; d < HD; d++)
            acc += query[h * HD + d] * w_kv[(size_t)(h * HD + d) * HH + j];
        ws[WS_QKP + h * HH + j] = acc * SCALE;
    } else if (blk == 36) {
        if (t < NH) {
            float acc = 0.f;
            for (int d = 0; d < HD; d++)
                acc += query[t * HD + d] * b_kv[t * HD + d];
            ws[WS_C + t] = acc * SCALE;
        }
    } else {
        // gate[i] = sigmoid(query . w_gate[i,:] + b_gate[i]); wave-per-output
        int lane = t & 63, wid = t >> 6;
        int base = (blk - 37) * 256 + wid * 64;
        for (int o = 0; o < 64; o++) {
            int i = base + o;
            float p = 0.f;
            #pragma unroll
            for (int k = 0; k < 12; k++)
                p += query[lane + 64 * k] * w_gate[(size_t)i * HH + lane + 64 * k];
            for (int off = 32; off; off >>= 1) p += __shfl_xor(p, off, 64);
            if (lane == 0) {
                float z = p + b_gate[i];
                ws[WS_GATE + i] = 1.0f / (1.0f + expf(-z));
            }
        }
    }
}

// ---------------- K1: scores[b][h][s] = x[b,s,:].qkp[h] + c[h] ----------------
__global__ __launch_bounds__(256) void k_scores(const float* __restrict__ x,
                                                const float* __restrict__ ws,
                                                float* __restrict__ sc) {
    __shared__ float qkp[NH * HH];
    int t = threadIdx.x;
    for (int i = t; i < NH * HH; i += 256) qkp[i] = ws[WS_QKP + i];
    float cc[NH];
    #pragma unroll
    for (int h = 0; h < NH; h++) cc[h] = ws[WS_C + h];
    __syncthreads();

    int blk = blockIdx.x;
    int b = blk >> 7;          // 128 chunks per batch
    int chunk = blk & 127;
    int wid = t >> 6, lane = t & 63;
    int s0 = chunk * 64 + wid * 16;
    const float* xb = x + (size_t)b * SS * HH;

    for (int g = 0; g < 4; g++) {
        int r0 = s0 + g * 4;
        float4 xv[4][3];
        #pragma unroll
        for (int r = 0; r < 4; r++)
            #pragma unroll
            for (int k = 0; k < 3; k++)
                xv[r][k] = *(const float4*)(xb + (size_t)(r0 + r) * HH + k * 256 + lane * 4);

        float acc[4][NH];
        #pragma unroll
        for (int r = 0; r < 4; r++)
            #pragma unroll
            for (int h = 0; h < NH; h++) acc[r][h] = 0.f;

        #pragma unroll
        for (int h = 0; h < NH; h++) {
            float4 qv[3];
            #pragma unroll
            for (int k = 0; k < 3; k++)
                qv[k] = *(const float4*)(&qkp[h * HH + k * 256 + lane * 4]);
            #pragma unroll
            for (int r = 0; r < 4; r++)
                #pragma unroll
                for (int k = 0; k < 3; k++) {
                    acc[r][h] += xv[r][k].x * qv[k].x;
                    acc[r][h] += xv[r][k].y * qv[k].y;
                    acc[r][h] += xv[r][k].z * qv[k].z;
                    acc[r][h] += xv[r][k].w * qv[k].w;
                }
        }

        #pragma unroll
        for (int r = 0; r < 4; r++)
            #pragma unroll
            for (int h = 0; h < NH; h++) {
                float v = acc[r][h];
                for (int off = 32; off; off >>= 1) v += __shfl_xor(v, off, 64);
                if (lane == 0)
                    sc[(size_t)(b * NH + h) * SS + (r0 + r)] = v + cc[h];
            }
    }
}

// ---------------- K2: softmax over S per (b,h); in-place ----------------
__global__ __launch_bounds__(256) void k_softmax(float* __restrict__ sc) {
    int bh = blockIdx.x;
    float* row = sc + (size_t)bh * SS;
    int t = threadIdx.x, lane = t & 63, wid = t >> 6;
    __shared__ float red[4];

    float m = -1e30f;
    for (int s = t; s < SS; s += 256) m = fmaxf(m, row[s]);
    for (int off = 32; off; off >>= 1) m = fmaxf(m, __shfl_xor(m, off, 64));
    if (lane == 0) red[wid] = m;
    __syncthreads();
    m = fmaxf(fmaxf(red[0], red[1]), fmaxf(red[2], red[3]));

    float l = 0.f;
    for (int s = t; s < SS; s += 256) l += expf(row[s] - m);
    for (int off = 32; off; off >>= 1) l += __shfl_xor(l, off, 64);
    __syncthreads();
    if (lane == 0) red[wid] = l;
    __syncthreads();
    l = red[0] + red[1] + red[2] + red[3];
    float inv = 1.0f / l;

    for (int s = t; s < SS; s += 256) row[s] = expf(row[s] - m) * inv;
}

// ---------------- K3: partial pooled[b,ch][h][j] = sum_{s in chunk} attn*x ----------------
__global__ __launch_bounds__(256) void k_pool(const float* __restrict__ x,
                                              const float* __restrict__ at_base,
                                              float* __restrict__ part) {
    int blk = blockIdx.x;
    int b = blk >> 5;          // 32 chunks of 256 rows
    int ch = blk & 31;
    int t = threadIdx.x;
    const float* xb = x + ((size_t)b * SS + ch * 256) * HH;
    const float* at = at_base + (size_t)b * NH * SS + ch * 256;

    float acc[NH][3];
    #pragma unroll
    for (int h = 0; h < NH; h++)
        #pragma unroll
        for (int k = 0; k < 3; k++) acc[h][k] = 0.f;

    for (int r = 0; r < 256; r++) {
        float w[NH];
        #pragma unroll
        for (int h = 0; h < NH; h++) w[h] = at[(size_t)h * SS + r];
        float x0 = xb[(size_t)r * HH + t];
        float x1 = xb[(size_t)r * HH + 256 + t];
        float x2 = xb[(size_t)r * HH + 512 + t];
        #pragma unroll
        for (int h = 0; h < NH; h++) {
            acc[h][0] += w[h] * x0;
            acc[h][1] += w[h] * x1;
            acc[h][2] += w[h] * x2;
        }
    }

    float* p = part + (size_t)(b * 32 + ch) * NH * HH;
    #pragma unroll
    for (int h = 0; h < NH; h++)
        #pragma unroll
        for (int k = 0; k < 3; k++)
            p[h * HH + k * 256 + t] = acc[h][k];
}

// ---------------- K4: reduce partials over 32 chunks ----------------
__global__ __launch_bounds__(256) void k_reduce(const float* __restrict__ part,
                                                float* __restrict__ pool) {
    int idx = blockIdx.x * 256 + threadIdx.x;
    if (idx >= BB * NH * HH) return;
    int b = idx / (NH * HH);
    int rem = idx - b * (NH * HH);
    float s = 0.f;
    #pragma unroll 8
    for (int ch = 0; ch < 32; ch++)
        s += part[(size_t)(b * 32 + ch) * NH * HH + rem];
    pool[idx] = s;
}

// ---------------- K5: o = gate * (W_out (W_v pooled + b_v) + b_out) ----------------
__global__ __launch_bounds__(256) void k_out(const float* __restrict__ ws,
                                             const float* __restrict__ w_kv,
                                             const float* __restrict__ b_kv,
                                             const float* __restrict__ w_out,
                                             const float* __restrict__ b_out,
                                             float* __restrict__ out) {
    __shared__ float pl[NH * HH];
    __shared__ float op[HH];
    int b = blockIdx.x, t = threadIdx.x;
    const float* pool = ws + WS_POOL + (size_t)b * NH * HH;
    for (int i = t; i < NH * HH; i += 256) pl[i] = pool[i];
    __syncthreads();

    #pragma unroll
    for (int ii = 0; ii < 3; ii++) {
        int hd = ii * 256 + t;
        int h = hd >> 6;
        const float* wr = w_kv + (size_t)(HH + hd) * HH;
        float acc = b_kv[HH + hd];
        #pragma unroll 8
        for (int j = 0; j < HH; j++) acc += wr[j] * pl[h * HH + j];
        op[hd] = acc;
    }
    __syncthreads();

    #pragma unroll
    for (int ii = 0; ii < 3; ii++) {
        int i = ii * 256 + t;
        const float* wr = w_out + (size_t)i * HH;
        float acc = b_out[i];
        #pragma unroll 8
        for (int c = 0; c < HH; c++) acc += wr[c] * op[c];
        out[(size_t)b * HH + i] = ws[WS_GATE + i] * acc;
    }
}

extern "C" void kernel_launch(void* const* d_in, const int* in_sizes, int n_in,
                              void* d_out, int out_size, void* d_ws, size_t ws_size,
                              hipStream_t stream) {
    const float* x      = (const float*)d_in[0];
    const float* query  = (const float*)d_in[1];
    const float* w_kv   = (const float*)d_in[2];
    const float* b_kv   = (const float*)d_in[3];
    const float* w_out  = (const float*)d_in[4];
    const float* b_out  = (const float*)d_in[5];
    const float* w_gate = (const float*)d_in[6];
    const float* b_gate = (const float*)d_in[7];
    float* ws  = (float*)d_ws;
    float* out = (float*)d_out;

    k_pre<<<40, 256, 0, stream>>>(query, w_kv, b_kv, w_gate, b_gate, ws);
    k_scores<<<BB * 128, 256, 0, stream>>>(x, ws, ws + WS_SC);
    k_softmax<<<BB * NH, 256, 0, stream>>>(ws + WS_SC);
    k_pool<<<BB * 32, 256, 0, stream>>>(x, ws + WS_SC, ws + WS_PART);
    k_reduce<<<(BB * NH * HH + 255) / 256, 256, 0, stream>>>(ws + WS_PART, ws + WS_POOL);
    k_out<<<BB, 256, 0, stream>>>(ws, w_kv, b_kv, w_out, b_out, out);
}